// Round 11
// baseline (119.847 us; speedup 1.0000x reference)
//
#include <hip/hip_runtime.h>
#include <math.h>

#define P 7
#define SCALE 0.125f
#define BB 4
#define CC 256
#define HH 128
#define WW 128
#define KK 512
#define NBIN 49
#define GPB 13            // bin-groups per ROI (4 bins each, 13*4 >= 49)
#define NXCD 8
#define RPX  (KK / NXCD)  // 64 ROIs per XCD slice

#define TRANS_BLOCKS 4096   // (HH*WW/64) * (CC/64) * BB
#define MASK_BLOCKS  4096   // KK*HH rows / 16 waves per block

__device__ __forceinline__ unsigned short f32_to_bf16_rne(float f) {
    unsigned int u = __float_as_uint(f);
    u += 0x7FFFu + ((u >> 16) & 1u);
    return (unsigned short)(u >> 16);
}

// Order-preserving bf16 -> u16 key. key 0 reserved = "empty/masked".
__device__ __forceinline__ unsigned short bf16_key(unsigned short b) {
    return (b & 0x8000u) ? (unsigned short)(~b) : (unsigned short)(b | 0x8000u);
}

__device__ __forceinline__ unsigned int pkmax_u16(unsigned int a, unsigned int b) {
    unsigned int d;
    asm("v_pk_max_u16 %0, %1, %2" : "=v"(d) : "v"(a), "v"(b));
    return d;
}

// extract 8 bits starting at s (0..127) from the 128-bit row mask
__device__ __forceinline__ unsigned int maskchunk(
    unsigned long long lo, unsigned long long hi, int s) {
    unsigned long long v;
    if (s >= 64)      v = hi >> (s - 64);
    else if (s == 0)  v = lo;
    else              v = (lo >> s) | (hi << (64 - s));
    return (unsigned int)(v & 0xFFu);
}

// ---- Fused prep: transpose+convert, mask->bitmask, ROI sort ----
__global__ __launch_bounds__(1024) void prep_fused(
    const float* __restrict__ in, const float* __restrict__ masks,
    const float* __restrict__ rois,
    unsigned short* __restrict__ out, unsigned long long* __restrict__ mbits,
    int* __restrict__ perm)
{
    __shared__ float tile[64][65];    // tile[channel][pixel]
    const int bid = blockIdx.x;
    const int tid = threadIdx.x;

    if (bid < TRANS_BLOCKS) {
        const int p0 = (bid & 255) * 64;        // pixel tile
        const int c0 = ((bid >> 8) & 3) * 64;   // channel tile
        const int b  = bid >> 10;               // batch
        const int tx = tid & 63;
        const int ty = tid >> 6;                // 0..15

        const float* src = in + (size_t)b * CC * (HH * WW);
#pragma unroll
        for (int j = 0; j < 64; j += 16)
            tile[ty + j][tx] =
                __builtin_nontemporal_load(&src[(size_t)(c0 + ty + j) * (HH * WW) + p0 + tx]);
        __syncthreads();

        unsigned int* dst = (unsigned int*)(out + (size_t)b * (HH * WW) * CC);
#pragma unroll
        for (int i = 0; i < 2; ++i) {
            const int flat = i * 1024 + tid;
            const int px = flat >> 5;
            const int cp = flat & 31;
            const unsigned int lo = bf16_key(f32_to_bf16_rne(tile[cp * 2][px]));
            const unsigned int hi = bf16_key(f32_to_bf16_rne(tile[cp * 2 + 1][px]));
            dst[((size_t)(p0 + px) * CC + c0) / 2 + cp] = lo | (hi << 16);
        }
    } else if (bid < TRANS_BLOCKS + MASK_BLOCKS) {
        const int mbid = bid - TRANS_BLOCKS;
        const int wv   = tid >> 6;              // 0..15
        const int lane = tid & 63;
        const int row  = mbid * 16 + wv;        // 0 .. KK*HH-1
        const float* mr = masks + (size_t)row * WW;
        const unsigned long long b0 = __ballot(mr[lane] > 0.5f);
        const unsigned long long b1 = __ballot(mr[64 + lane] > 0.5f);
        if (lane == 0) {
            mbits[(size_t)row * 2]     = b0;
            mbits[(size_t)row * 2 + 1] = b1;
        }
    } else {
        // deterministic rank sort of 512 ROIs by key=(batch,row-start)
        __shared__ int skey[KK];
        if (tid < KK) {
            const float* r = rois + (size_t)tid * 5;
            const int b  = (int)r[0];
            int sh = (int)rintf(r[2] * SCALE);
            sh = min(max(sh, 0), HH - 1);
            skey[tid] = b * HH + sh;
        }
        __syncthreads();
        if (tid < KK) {
            const int mykey = skey[tid];
            int pos = 0;
            for (int j = 0; j < KK; ++j) {
                const int kj = skey[j];
                pos += (kj < mykey) || (kj == mykey && j < tid);
            }
            perm[pos] = tid;
        }
    }
}

// ---- Pool: one wave per bin, software-pipelined chunk stream ----
__global__ __launch_bounds__(256) void pool_key(
    const unsigned int* __restrict__ fbase,         // [B,HW,C/2] packed keys
    const float* __restrict__ rois,                 // [K,5]
    const unsigned long long* __restrict__ mbits,   // [K,H,2]
    const int* __restrict__ perm,                   // [K] sorted ROI order
    float* __restrict__ out)                        // [K,C,P,P]
{
    // XCD x processes sorted-slice [x*64, x*64+64)
    const int pid = blockIdx.x;
    const int x   = pid & (NXCD - 1);
    const int t   = pid >> 3;
    const int g   = t % GPB;
    const int q   = t / GPB;                // 0..63
    const int k   = perm[x * RPX + q];

    const int wv   = threadIdx.x >> 6;
    const int lane = threadIdx.x & 63;
    const int bi   = g * 4 + wv;
    if (bi >= NBIN) return;                 // wave-uniform
    const int ph = bi / P;
    const int pw = bi % P;

    const int half = lane >> 5;             // even/odd pixel of each pair
    const int c4   = (lane & 31) * 4;       // uint offset: 8 channels

    const float* roi = rois + (size_t)k * 5;
    const int b  = (int)roi[0];
    const int sw = (int)rintf(roi[1] * SCALE);
    const int sh = (int)rintf(roi[2] * SCALE);
    const int ew = (int)rintf(roi[3] * SCALE);
    const int eh = (int)rintf(roi[4] * SCALE);
    const int roi_w = max(ew - sw + 1, 1);
    const int roi_h = max(eh - sh + 1, 1);

    const int hs = min(max((ph * roi_h) / P + sh, 0), HH);
    const int he = min(max(((ph + 1) * roi_h + P - 1) / P + sh, 0), HH);
    const int wl = min(max((pw * roi_w) / P + sw, 0), WW);
    const int wr = min(max(((pw + 1) * roi_w + P - 1) / P + sw, 0), WW);

    const unsigned int boff = (unsigned int)b * (HH * WW * (CC / 2));
    const unsigned long long* mrow = mbits + (size_t)k * HH * 2;

    unsigned int a0 = 0, a1 = 0, a2 = 0, a3 = 0;   // packed key accumulators

    const int bw   = wr - wl;
    const int cpr  = (bw + 7) >> 3;                 // chunks per row
    const int nch  = (he - hs) * ((bw > 0) ? cpr : 0);
    const unsigned int lastmask = (bw & 7) ? ((1u << (bw & 7)) - 1u) : 0xFFu;

    // prefetch / consume pointers over the flattened (row, chunk) stream
    int pf_h = hs, pf_c = 0;
    int cs_h = hs, cs_c = 0;

    uint4 A0, A1, A2, A3, B0, B1, B2, B3;
    unsigned long long mlA = 0, mhA = 0, mlB = 0, mhB = 0;
    int sA = 0, sB = 0;
    unsigned int lfA = 0, lfB = 0;

#define LOAD_CHUNK(D0, D1, D2, D3, ML, MH, SS, LF) do {                        \
        const unsigned int ro = boff + (unsigned int)pf_h * (WW * (CC / 2));   \
        const int wb = wl + pf_c * 8 + half;                                   \
        D0 = *(const uint4*)(fbase + ro + (unsigned int)min(wb,     wr - 1) * (CC / 2) + c4); \
        D1 = *(const uint4*)(fbase + ro + (unsigned int)min(wb + 2, wr - 1) * (CC / 2) + c4); \
        D2 = *(const uint4*)(fbase + ro + (unsigned int)min(wb + 4, wr - 1) * (CC / 2) + c4); \
        D3 = *(const uint4*)(fbase + ro + (unsigned int)min(wb + 6, wr - 1) * (CC / 2) + c4); \
        ML = mrow[2 * pf_h]; MH = mrow[2 * pf_h + 1];                          \
        SS = wl + pf_c * 8;                                                    \
        LF = (pf_c == cpr - 1) ? lastmask : 0xFFu;                             \
        if (++pf_c == cpr) { pf_c = 0; ++pf_h; }                               \
    } while (0)

#define CONSUME(D0, D1, D2, D3, ML, MH, SS, LF) do {                           \
        unsigned int chunk = maskchunk(ML, MH, SS) & LF;                       \
        const unsigned int m0 = 0u - ((chunk >> (0 + half)) & 1u);             \
        const unsigned int m1 = 0u - ((chunk >> (2 + half)) & 1u);             \
        const unsigned int m2 = 0u - ((chunk >> (4 + half)) & 1u);             \
        const unsigned int m3 = 0u - ((chunk >> (6 + half)) & 1u);             \
        a0 = pkmax_u16(a0, D0.x & m0); a1 = pkmax_u16(a1, D0.y & m0);          \
        a2 = pkmax_u16(a2, D0.z & m0); a3 = pkmax_u16(a3, D0.w & m0);          \
        a0 = pkmax_u16(a0, D1.x & m1); a1 = pkmax_u16(a1, D1.y & m1);          \
        a2 = pkmax_u16(a2, D1.z & m1); a3 = pkmax_u16(a3, D1.w & m1);          \
        a0 = pkmax_u16(a0, D2.x & m2); a1 = pkmax_u16(a1, D2.y & m2);          \
        a2 = pkmax_u16(a2, D2.z & m2); a3 = pkmax_u16(a3, D2.w & m2);          \
        a0 = pkmax_u16(a0, D3.x & m3); a1 = pkmax_u16(a1, D3.y & m3);          \
        a2 = pkmax_u16(a2, D3.z & m3); a3 = pkmax_u16(a3, D3.w & m3);          \
    } while (0)

    if (nch > 0) {
        LOAD_CHUNK(A0, A1, A2, A3, mlA, mhA, sA, lfA);          // chunk 0
        for (int i = 0; i + 1 < nch; i += 2) {
            LOAD_CHUNK(B0, B1, B2, B3, mlB, mhB, sB, lfB);      // chunk i+1
            CONSUME(A0, A1, A2, A3, mlA, mhA, sA, lfA);         // chunk i
            if (i + 2 < nch)
                LOAD_CHUNK(A0, A1, A2, A3, mlA, mhA, sA, lfA);  // chunk i+2
            CONSUME(B0, B1, B2, B3, mlB, mhB, sB, lfB);         // chunk i+1
        }
        if (nch & 1)
            CONSUME(A0, A1, A2, A3, mlA, mhA, sA, lfA);         // last odd
    }

#undef LOAD_CHUNK
#undef CONSUME

    // combine pixel-halves (lane i <-> i+32 hold same channels)
    a0 = pkmax_u16(a0, (unsigned int)__shfl_xor((int)a0, 32, 64));
    a1 = pkmax_u16(a1, (unsigned int)__shfl_xor((int)a1, 32, 64));
    a2 = pkmax_u16(a2, (unsigned int)__shfl_xor((int)a2, 32, 64));
    a3 = pkmax_u16(a3, (unsigned int)__shfl_xor((int)a3, 32, 64));

    if (half == 0) {
        const unsigned int acc[4] = {a0, a1, a2, a3};
        float* o = out + ((size_t)k * CC + (size_t)c4 * 2) * NBIN + ph * P + pw;
#pragma unroll
        for (int j = 0; j < 8; ++j) {
            const unsigned int d = acc[j >> 1];
            const unsigned int key = (j & 1) ? (d >> 16) : (d & 0xFFFFu);
            float r;
            if (key == 0u) {
                r = 0.0f;                       // empty / fully-masked bin
            } else {
                const unsigned int bbits =
                    (key & 0x8000u) ? (key ^ 0x8000u) : (~key & 0xFFFFu);
                r = __uint_as_float(bbits << 16);
            }
            o[(size_t)j * NBIN] = r;
        }
    }
}

// ---------- Fallback (NCHW direct, correctness-only path) ----------
__global__ __launch_bounds__(256) void ROIPool_nchw_kernel(
    const float* __restrict__ inputs, const float* __restrict__ rois,
    const float* __restrict__ masks, float* __restrict__ out)
{
    const int k  = blockIdx.x;
    const int ph = blockIdx.y;
    const int c  = threadIdx.x;

    const float* roi = rois + k * 5;
    const int b  = (int)roi[0];
    const int sw = (int)rintf(roi[1] * SCALE);
    const int sh = (int)rintf(roi[2] * SCALE);
    const int ew = (int)rintf(roi[3] * SCALE);
    const int eh = (int)rintf(roi[4] * SCALE);
    const int roi_w = max(ew - sw + 1, 1);
    const int roi_h = max(eh - sh + 1, 1);

    const int hs = min(max((ph * roi_h) / P + sh, 0), HH);
    const int he = min(max(((ph + 1) * roi_h + P - 1) / P + sh, 0), HH);

    int wsb[P], web[P];
#pragma unroll
    for (int pw = 0; pw < P; ++pw) {
        wsb[pw] = min(max((pw * roi_w) / P + sw, 0), WW);
        web[pw] = min(max(((pw + 1) * roi_w + P - 1) / P + sw, 0), WW);
    }

    const float* f = inputs + ((size_t)b * CC + c) * (HH * WW);
    const float* m = masks  + (size_t)k * (HH * WW);

    float vmax[P];
#pragma unroll
    for (int pw = 0; pw < P; ++pw) vmax[pw] = -INFINITY;

    for (int h = hs; h < he; ++h) {
        const float* frow = f + h * WW;
        const float* mrow = m + h * WW;
#pragma unroll
        for (int pw = 0; pw < P; ++pw) {
            float v = vmax[pw];
            for (int w = wsb[pw]; w < web[pw]; ++w)
                if (mrow[w] > 0.5f) v = fmaxf(v, frow[w]);
            vmax[pw] = v;
        }
    }

    float* o = out + (((size_t)k * CC + c) * P + ph) * P;
#pragma unroll
    for (int pw = 0; pw < P; ++pw) {
        const float v = vmax[pw];
        o[pw] = isinf(v) ? 0.0f : v;
    }
}

extern "C" void kernel_launch(void* const* d_in, const int* in_sizes, int n_in,
                              void* d_out, int out_size, void* d_ws, size_t ws_size,
                              hipStream_t stream) {
    const float* inputs = (const float*)d_in[0];
    const float* rois   = (const float*)d_in[1];
    const float* masks  = (const float*)d_in[2];
    float* out = (float*)d_out;

    const size_t keys_bytes  = (size_t)BB * CC * HH * WW * sizeof(unsigned short); // 32 MiB
    const size_t mbits_bytes = (size_t)KK * HH * 2 * sizeof(unsigned long long);   // 1 MiB
    const size_t perm_bytes  = (size_t)KK * sizeof(int);                           // 2 KiB

    if (ws_size >= keys_bytes + mbits_bytes + perm_bytes) {
        unsigned short* fT = (unsigned short*)d_ws;
        unsigned long long* mb = (unsigned long long*)((char*)d_ws + keys_bytes);
        int* perm = (int*)((char*)d_ws + keys_bytes + mbits_bytes);
        {
            dim3 grid(TRANS_BLOCKS + MASK_BLOCKS + 1);
            dim3 block(1024);
            prep_fused<<<grid, block, 0, stream>>>(inputs, masks, rois, fT, mb, perm);
        }
        {
            dim3 grid(KK * GPB);
            dim3 block(256);
            pool_key<<<grid, block, 0, stream>>>((const unsigned int*)fT, rois, mb, perm, out);
        }
    } else {
        dim3 grid(KK, P);
        dim3 block(CC);
        ROIPool_nchw_kernel<<<grid, block, 0, stream>>>(inputs, rois, masks, out);
    }
}

// Round 12
// 113.951 us; speedup vs baseline: 1.0517x; 1.0517x over previous
//
#include <hip/hip_runtime.h>
#include <math.h>

#define P 7
#define SCALE 0.125f
#define BB 4
#define CC 256
#define HH 128
#define WW 128
#define KK 512
#define NBIN 49
#define GPB 13            // bin-groups per ROI (4 bins each, 13*4 >= 49)
#define NXCD 8
#define RPX  (KK / NXCD)  // 64 ROIs per XCD slice

#define TRANS_BLOCKS 4096   // (HH*WW/64) * (CC/64) * BB
#define MASK_BLOCKS  4096   // KK*HH rows / 16 waves per block

__device__ __forceinline__ unsigned short f32_to_bf16_rne(float f) {
    unsigned int u = __float_as_uint(f);
    u += 0x7FFFu + ((u >> 16) & 1u);
    return (unsigned short)(u >> 16);
}

// Order-preserving bf16 -> u16 key. key 0 reserved = "empty/masked".
__device__ __forceinline__ unsigned short bf16_key(unsigned short b) {
    return (b & 0x8000u) ? (unsigned short)(~b) : (unsigned short)(b | 0x8000u);
}

__device__ __forceinline__ unsigned int pkmax_u16(unsigned int a, unsigned int b) {
    unsigned int d;
    asm("v_pk_max_u16 %0, %1, %2" : "=v"(d) : "v"(a), "v"(b));
    return d;
}

// ---- Fused prep: transpose+convert, mask->bitmask; block 0 also sorts ----
__global__ __launch_bounds__(1024) void prep_fused(
    const float* __restrict__ in, const float* __restrict__ masks,
    const float* __restrict__ rois,
    unsigned short* __restrict__ out, unsigned long long* __restrict__ mbits,
    int* __restrict__ perm)
{
    __shared__ float tile[64][65];    // tile[channel][pixel]
    __shared__ int skey[KK];          // used by block 0 only (sort)
    const int bid = blockIdx.x;
    const int tid = threadIdx.x;

    if (bid < TRANS_BLOCKS) {
        const int p0 = (bid & 255) * 64;        // pixel tile
        const int c0 = ((bid >> 8) & 3) * 64;   // channel tile
        const int b  = bid >> 10;               // batch
        const int tx = tid & 63;
        const int ty = tid >> 6;                // 0..15

        const float* src = in + (size_t)b * CC * (HH * WW);
#pragma unroll
        for (int j = 0; j < 64; j += 16)
            tile[ty + j][tx] =
                __builtin_nontemporal_load(&src[(size_t)(c0 + ty + j) * (HH * WW) + p0 + tx]);
        __syncthreads();

        unsigned int* dst = (unsigned int*)(out + (size_t)b * (HH * WW) * CC);
#pragma unroll
        for (int i = 0; i < 2; ++i) {
            const int flat = i * 1024 + tid;
            const int px = flat >> 5;
            const int cp = flat & 31;
            const unsigned int lo = bf16_key(f32_to_bf16_rne(tile[cp * 2][px]));
            const unsigned int hi = bf16_key(f32_to_bf16_rne(tile[cp * 2 + 1][px]));
            dst[((size_t)(p0 + px) * CC + c0) / 2 + cp] = lo | (hi << 16);
        }

        if (bid == 0) {
            // deterministic rank sort of 512 ROIs by key=(batch,start-row).
            // Block 0 is dispatched first: this extra work hides under the
            // other ~8K blocks (the old dedicated tail block cost ~11 us).
            __syncthreads();
            if (tid < KK) {
                const float* r = rois + (size_t)tid * 5;
                const int rb = (int)r[0];
                int rsh = (int)rintf(r[2] * SCALE);
                rsh = min(max(rsh, 0), HH - 1);
                skey[tid] = rb * HH + rsh;
            }
            __syncthreads();
            if (tid < KK) {
                const int mykey = skey[tid];
                int pos = 0;
                for (int j = 0; j < KK; ++j) {
                    const int kj = skey[j];
                    pos += (kj < mykey) || (kj == mykey && j < tid);
                }
                perm[pos] = tid;
            }
        }
    } else {
        const int mbid = bid - TRANS_BLOCKS;
        const int wv   = tid >> 6;              // 0..15
        const int lane = tid & 63;
        const int row  = mbid * 16 + wv;        // 0 .. KK*HH-1
        const float* mr = masks + (size_t)row * WW;
        const unsigned long long b0 = __ballot(mr[lane] > 0.5f);
        const unsigned long long b1 = __ballot(mr[64 + lane] > 0.5f);
        if (lane == 0) {
            mbits[(size_t)row * 2]     = b0;
            mbits[(size_t)row * 2 + 1] = b1;
        }
    }
}

// ---- Pool: one wave per bin, SALU mask path, imm-offset loads ----
__global__ __launch_bounds__(256) void pool_key(
    const unsigned int* __restrict__ fbase,         // [B,HW,C/2] packed keys
    const float* __restrict__ rois,                 // [K,5]
    const unsigned long long* __restrict__ mbits,   // [K,H,2]
    const int* __restrict__ perm,                   // [K] sorted ROI order
    float* __restrict__ out)                        // [K,C,P,P]
{
    // XCD x processes sorted-slice [x*64, x*64+64)
    const int pid = blockIdx.x;
    const int x   = pid & (NXCD - 1);
    const int t   = pid >> 3;
    const int g   = t % GPB;
    const int q   = t / GPB;                // 0..63
    const int k   = __builtin_amdgcn_readfirstlane(perm[x * RPX + q]);

    const int wv   = threadIdx.x >> 6;
    const int lane = threadIdx.x & 63;
    const int bi   = g * 4 + wv;
    if (bi >= NBIN) return;                 // wave-uniform
    const int ph = bi / P;
    const int pw = bi % P;

    const int half = lane >> 5;             // even/odd pixel of each pair
    const int c4   = (lane & 31) * 4;       // uint offset: 8 channels

    const float* roi = rois + (size_t)k * 5;
    const int b  = __builtin_amdgcn_readfirstlane((int)roi[0]);
    const int sw = (int)rintf(roi[1] * SCALE);
    const int sh = (int)rintf(roi[2] * SCALE);
    const int ew = (int)rintf(roi[3] * SCALE);
    const int eh = (int)rintf(roi[4] * SCALE);
    const int roi_w = max(ew - sw + 1, 1);
    const int roi_h = max(eh - sh + 1, 1);

    // wave-uniform bin bounds -> SGPRs (SALU loop control + scalar mask math)
    const int hs = __builtin_amdgcn_readfirstlane(min(max((ph * roi_h) / P + sh, 0), HH));
    const int he = __builtin_amdgcn_readfirstlane(min(max(((ph + 1) * roi_h + P - 1) / P + sh, 0), HH));
    const int wl = __builtin_amdgcn_readfirstlane(min(max((pw * roi_w) / P + sw, 0), WW));
    const int wr = __builtin_amdgcn_readfirstlane(min(max(((pw + 1) * roi_w + P - 1) / P + sw, 0), WW));

    const unsigned int* fb = fbase
        + (unsigned int)b * (unsigned int)(HH * WW * (CC / 2))
        + (unsigned int)(half * (CC / 2) + c4);
    const unsigned long long* mrow = mbits + (size_t)k * (HH * 2);

    unsigned int a0 = 0, a1 = 0, a2 = 0, a3 = 0;   // packed key accumulators

    const int sh0 = 0 + half, sh1 = 2 + half, sh2 = 4 + half, sh3 = 6 + half;

#pragma unroll 4
    for (int h = hs; h < he; ++h) {
        const unsigned long long lov = mrow[2 * h];
        const unsigned long long hiv = mrow[2 * h + 1];
        // mask words are wave-uniform: move to SGPRs so the funnel shift and
        // chunk masking run on the (dual-issued) SALU pipe
        const unsigned int ll  = __builtin_amdgcn_readfirstlane((unsigned int)lov);
        const unsigned int lh  = __builtin_amdgcn_readfirstlane((unsigned int)(lov >> 32));
        const unsigned int hl  = __builtin_amdgcn_readfirstlane((unsigned int)hiv);
        const unsigned int hh2 = __builtin_amdgcn_readfirstlane((unsigned int)(hiv >> 32));
        const unsigned long long lo = ((unsigned long long)lh << 32) | ll;
        const unsigned long long hi = ((unsigned long long)hh2 << 32) | hl;

        const unsigned int* frow = fb + (unsigned int)h * (unsigned int)(WW * (CC / 2));
        for (int w0 = wl; w0 < wr; w0 += 8) {
            unsigned long long v;
            if (w0 >= 64)      v = hi >> (w0 - 64);
            else if (w0 == 0)  v = lo;
            else               v = (lo >> w0) | (hi << (64 - w0));
            unsigned int chunk = (unsigned int)v & 0xFFu;
            const int n = wr - w0;                       // valid pixel count
            chunk &= (n >= 8) ? 0xFFu : ((1u << n) - 1u);

            // one base; pixel pairs at immediate offsets (1 KB apart).
            // Over-read past wr is masked off; memory valid (mbits region
            // follows the 32 MiB key buffer; max spill ~3.7 KB).
            const unsigned int* basep = frow + (unsigned int)w0 * (CC / 2);
            const uint4 k0 = *(const uint4*)(basep);
            const uint4 k1 = *(const uint4*)(basep + 256);
            const uint4 k2 = *(const uint4*)(basep + 512);
            const uint4 k3 = *(const uint4*)(basep + 768);

            const unsigned int m0 = 0u - ((chunk >> sh0) & 1u);
            const unsigned int m1 = 0u - ((chunk >> sh1) & 1u);
            const unsigned int m2 = 0u - ((chunk >> sh2) & 1u);
            const unsigned int m3 = 0u - ((chunk >> sh3) & 1u);

            a0 = pkmax_u16(a0, k0.x & m0); a1 = pkmax_u16(a1, k0.y & m0);
            a2 = pkmax_u16(a2, k0.z & m0); a3 = pkmax_u16(a3, k0.w & m0);
            a0 = pkmax_u16(a0, k1.x & m1); a1 = pkmax_u16(a1, k1.y & m1);
            a2 = pkmax_u16(a2, k1.z & m1); a3 = pkmax_u16(a3, k1.w & m1);
            a0 = pkmax_u16(a0, k2.x & m2); a1 = pkmax_u16(a1, k2.y & m2);
            a2 = pkmax_u16(a2, k2.z & m2); a3 = pkmax_u16(a3, k2.w & m2);
            a0 = pkmax_u16(a0, k3.x & m3); a1 = pkmax_u16(a1, k3.y & m3);
            a2 = pkmax_u16(a2, k3.z & m3); a3 = pkmax_u16(a3, k3.w & m3);
        }
    }

    // combine pixel-halves (lane i <-> i+32 hold same channels)
    a0 = pkmax_u16(a0, (unsigned int)__shfl_xor((int)a0, 32, 64));
    a1 = pkmax_u16(a1, (unsigned int)__shfl_xor((int)a1, 32, 64));
    a2 = pkmax_u16(a2, (unsigned int)__shfl_xor((int)a2, 32, 64));
    a3 = pkmax_u16(a3, (unsigned int)__shfl_xor((int)a3, 32, 64));

    if (half == 0) {
        const unsigned int acc[4] = {a0, a1, a2, a3};
        float* o = out + ((size_t)k * CC + (size_t)c4 * 2) * NBIN + ph * P + pw;
#pragma unroll
        for (int j = 0; j < 8; ++j) {
            const unsigned int d = acc[j >> 1];
            const unsigned int key = (j & 1) ? (d >> 16) : (d & 0xFFFFu);
            float r;
            if (key == 0u) {
                r = 0.0f;                       // empty / fully-masked bin
            } else {
                const unsigned int bbits =
                    (key & 0x8000u) ? (key ^ 0x8000u) : (~key & 0xFFFFu);
                r = __uint_as_float(bbits << 16);
            }
            o[(size_t)j * NBIN] = r;
        }
    }
}

// ---------- Fallback (NCHW direct, correctness-only path) ----------
__global__ __launch_bounds__(256) void ROIPool_nchw_kernel(
    const float* __restrict__ inputs, const float* __restrict__ rois,
    const float* __restrict__ masks, float* __restrict__ out)
{
    const int k  = blockIdx.x;
    const int ph = blockIdx.y;
    const int c  = threadIdx.x;

    const float* roi = rois + k * 5;
    const int b  = (int)roi[0];
    const int sw = (int)rintf(roi[1] * SCALE);
    const int sh = (int)rintf(roi[2] * SCALE);
    const int ew = (int)rintf(roi[3] * SCALE);
    const int eh = (int)rintf(roi[4] * SCALE);
    const int roi_w = max(ew - sw + 1, 1);
    const int roi_h = max(eh - sh + 1, 1);

    const int hs = min(max((ph * roi_h) / P + sh, 0), HH);
    const int he = min(max(((ph + 1) * roi_h + P - 1) / P + sh, 0), HH);

    int wsb[P], web[P];
#pragma unroll
    for (int pw = 0; pw < P; ++pw) {
        wsb[pw] = min(max((pw * roi_w) / P + sw, 0), WW);
        web[pw] = min(max(((pw + 1) * roi_w + P - 1) / P + sw, 0), WW);
    }

    const float* f = inputs + ((size_t)b * CC + c) * (HH * WW);
    const float* m = masks  + (size_t)k * (HH * WW);

    float vmax[P];
#pragma unroll
    for (int pw = 0; pw < P; ++pw) vmax[pw] = -INFINITY;

    for (int h = hs; h < he; ++h) {
        const float* frow = f + h * WW;
        const float* mrow = m + h * WW;
#pragma unroll
        for (int pw = 0; pw < P; ++pw) {
            float v = vmax[pw];
            for (int w = wsb[pw]; w < web[pw]; ++w)
                if (mrow[w] > 0.5f) v = fmaxf(v, frow[w]);
            vmax[pw] = v;
        }
    }

    float* o = out + (((size_t)k * CC + c) * P + ph) * P;
#pragma unroll
    for (int pw = 0; pw < P; ++pw) {
        const float v = vmax[pw];
        o[pw] = isinf(v) ? 0.0f : v;
    }
}

extern "C" void kernel_launch(void* const* d_in, const int* in_sizes, int n_in,
                              void* d_out, int out_size, void* d_ws, size_t ws_size,
                              hipStream_t stream) {
    const float* inputs = (const float*)d_in[0];
    const float* rois   = (const float*)d_in[1];
    const float* masks  = (const float*)d_in[2];
    float* out = (float*)d_out;

    const size_t keys_bytes  = (size_t)BB * CC * HH * WW * sizeof(unsigned short); // 32 MiB
    const size_t mbits_bytes = (size_t)KK * HH * 2 * sizeof(unsigned long long);   // 1 MiB
    const size_t perm_bytes  = (size_t)KK * sizeof(int);                           // 2 KiB

    if (ws_size >= keys_bytes + mbits_bytes + perm_bytes) {
        unsigned short* fT = (unsigned short*)d_ws;
        unsigned long long* mb = (unsigned long long*)((char*)d_ws + keys_bytes);
        int* perm = (int*)((char*)d_ws + keys_bytes + mbits_bytes);
        {
            dim3 grid(TRANS_BLOCKS + MASK_BLOCKS);
            dim3 block(1024);
            prep_fused<<<grid, block, 0, stream>>>(inputs, masks, rois, fT, mb, perm);
        }
        {
            dim3 grid(KK * GPB);
            dim3 block(256);
            pool_key<<<grid, block, 0, stream>>>((const unsigned int*)fT, rois, mb, perm, out);
        }
    } else {
        dim3 grid(KK, P);
        dim3 block(CC);
        ROIPool_nchw_kernel<<<grid, block, 0, stream>>>(inputs, rois, masks, out);
    }
}